// Round 8
// baseline (559.119 us; speedup 1.0000x reference)
//
#include <hip/hip_runtime.h>
#include <math.h>

#define Dn 256
#define Hn 64

typedef __attribute__((ext_vector_type(8))) short short8;
typedef __attribute__((ext_vector_type(4))) float floatx4;
typedef __attribute__((ext_vector_type(4))) unsigned int uint4v;

static __device__ __forceinline__ unsigned short f2bf(float x) {
    unsigned int u = __float_as_uint(x);
    unsigned int r = (u + 0x7fffu + ((u >> 16) & 1u)) >> 16;   // RNE
    return (unsigned short)r;
}

// async global -> LDS, dest = wave-uniform base + lane*size (HW rule, m104)
static __device__ __forceinline__ void gll16(const unsigned short* g, unsigned short* l) {
    __builtin_amdgcn_global_load_lds(
        (const __attribute__((address_space(1))) unsigned int*)g,
        (__attribute__((address_space(3))) unsigned int*)l, 16, 0, 0);
}
static __device__ __forceinline__ void gll4(const float* g, float* l) {
    __builtin_amdgcn_global_load_lds(
        (const __attribute__((address_space(1))) unsigned int*)g,
        (__attribute__((address_space(3))) unsigned int*)l, 4, 0, 0);
}

// ---------------------------------------------------------------------------
// prep_sgm: sgm[i*Dn + j] = sigmoid(adj[j*Dn + i]) * (j != i)
// grid 256 (i), block 256 (j)
// ---------------------------------------------------------------------------
__global__ __launch_bounds__(256) void prep_sgm(const float* __restrict__ adj,
                                                float* __restrict__ sgm) {
    const int i = blockIdx.x, j = threadIdx.x;
    float m = 0.f;
    if (j != i) m = 1.f / (1.f + __expf(-adj[(size_t)j * Dn + i]));
    sgm[(size_t)i * Dn + j] = m;
}

// ---------------------------------------------------------------------------
// prep_wb: masked bf16 weights in MFMA fragment layout (validated R2/v2/v4).
// Fragment (i, c, nb, lane, e) <-> kk = nb*16 + (lane&15), j = c*32 + (lane>>4)*8 + e
// Wb offset (ushort): (((i*8 + c)*4 + nb)*64 + lane)*8 + e
// Used as the A-operand of mfma(W, Z): M-index = lane&15 = hidden.
// grid (8, 256) = (c, i), block 256
// ---------------------------------------------------------------------------
__global__ __launch_bounds__(256) void prep_wb(const float* __restrict__ W1,
                                               const float* __restrict__ sgm,
                                               unsigned short* __restrict__ Wb) {
    const int c = blockIdx.x, i = blockIdx.y;
    const int t = threadIdx.x;
    const int nb = t >> 6, l = t & 63;
    const int kk = nb * 16 + (l & 15);
    const int jb = c * 32 + ((l >> 4) & 3) * 8;
    const float* wp = W1 + ((size_t)i * Hn + kk) * Dn + jb;
    const float* sp = sgm + (size_t)i * Dn + jb;
    unsigned short v[8];
#pragma unroll
    for (int e = 0; e < 8; ++e) v[e] = f2bf(wp[e] * sp[e]);
    unsigned short* dst = Wb + ((((size_t)i * 8 + c) * 4 + nb) * 64 + l) * 8;
    *(short8*)dst = *(const short8*)v;
}

// ---------------------------------------------------------------------------
// prep_nst: nsT[d*B + b] = exp(log_sigma[d]) * noise[b*Dn + d]  (64x64 tiles)
// grid (B/64, Dn/64), block 256
// ---------------------------------------------------------------------------
__global__ __launch_bounds__(256) void prep_nst(const float* __restrict__ noise,
                                                const float* __restrict__ ls,
                                                float* __restrict__ nsT, int B) {
    __shared__ float tile[64][65];
    const int bi = blockIdx.x * 64, dj = blockIdx.y * 64;
    const int t = threadIdx.x, c = t & 63, rq = t >> 6;
#pragma unroll
    for (int it = 0; it < 16; ++it) {
        int b = bi + it * 4 + rq;
        tile[it * 4 + rq][c] = noise[(size_t)b * Dn + dj + c];
    }
    __syncthreads();
#pragma unroll
    for (int it = 0; it < 16; ++it) {
        int d = dj + it * 4 + rq;
        float sg = __expf(ls[d]);
        nsT[(size_t)d * B + bi + c] = tile[c][it * 4 + rq] * sg;
    }
}

// ---------------------------------------------------------------------------
// scm_main (v8): v3's PASSED gll->LDS staging + v4's PASSED register-z math,
// with the gll issue PINNED early by a second sched_barrier(0).
//   Why: v3's glls (distance-1, correct) could legally sink to the body end
//   (only the NEXT step's fence bounded them) -> ~zero in-flight time ->
//   full L2 latency exposed every step (its 4800 cyc/step). v4/v5/v6/v7
//   showed register prefetch is uncontrollable (compiler sink / regalloc
//   races). v8: weights + scalars live ONLY in LDS (zero weight VGPRs),
//   staged by global_load_lds distance-1 into a parity ring; step top:
//     s_waitcnt vmcnt(0)   (free: loads had a full step in flight)
//     sched_barrier(0)
//     [gll block for row i+1 -> slot (i+1)&1]   <- trapped here by...
//     sched_barrier(0)
//     ds_read slot i&1 -> MFMAs -> epilogue (silu dot, 2 shfl, reg-z insert)
//   z history entirely in registers (af[8] + ain, v4-validated insert).
//   Slot parity is compile-time (i&1 == e8&1). No __syncthreads anywhere;
//   both LDS regions wave-private. Out-stores batched 8 steps (v1 pattern).
// grid: B/32, block 128. LDS 132 KB -> 1 block/CU, 2 waves/CU.
// ---------------------------------------------------------------------------
__global__ __launch_bounds__(128, 1) void scm_main(const unsigned short* __restrict__ Wb,
                                                   const float* __restrict__ b1,
                                                   const float* __restrict__ W2,
                                                   const float* __restrict__ b2,
                                                   const float* __restrict__ nsT,
                                                   float* __restrict__ out, int B) {
    // [slot][wave][chunk][nb][lane*8] -- exact Wb fragment bytes, lane-linear
    __shared__ __align__(16) unsigned short ring[2][2][8][4][512];   // 128 KB
    // [slot][wave][0..63]=b1row [64..127]=W2row [128..191]=nv [192..255]=b2
    __shared__ __align__(16) float sring[2][2][256];                 // 4 KB

    const int t = threadIdx.x;
    const int w = t >> 6, l = t & 63;
    const int n = l & 15, q = l >> 4;
    const int rowbase = blockIdx.x * 32 + w * 16;

    short8 af[8];                        // frozen z chunks (registers)
    uint4v ain = {0u, 0u, 0u, 0u};       // in-progress z chunk (registers)
    const floatx4 zf4 = {0.f, 0.f, 0.f, 0.f};

    // prologue: stage row-0 scalars into slot 0 (row 0 needs no weights: z==0)
    gll4(b1 + l,            &sring[0][w][0]);
    gll4(W2 + l,            &sring[0][w][64]);
    gll4(nsT + rowbase + n, &sring[0][w][128]);
    gll4(b2,                &sring[0][w][192]);

#pragma unroll
    for (int sec = 0; sec < 8; ++sec) {
        if (sec > 0) {
            af[sec - 1] = __builtin_bit_cast(short8, ain);   // register copy
            ain = (uint4v){0u, 0u, 0u, 0u};
        }
#pragma unroll 1
        for (int ii8 = 0; ii8 < 4; ++ii8) {
            float zz[8];
#pragma unroll
            for (int e8 = 0; e8 < 8; ++e8) {
                const int ii = ii8 * 8 + e8;
                const int i  = sec * 32 + ii;
                const int sl = e8 & 1;          // compile-time slot parity
                const int ns = sl ^ 1;

                // slot sl's loads were issued one full step ago: drain is free
                asm volatile("s_waitcnt vmcnt(0)" ::: "memory");
                __builtin_amdgcn_sched_barrier(0);

                // ---- stage row i+1 into slot ns (pinned EARLY in the body) ----
                if (i < 255) {
                    const int ip = i + 1;
                    const unsigned short* wrow = Wb + (size_t)ip * 16384 + (size_t)l * 8;
                    // chunks 0..sec cover everything step ip consumes
                    // (at ii==31, ip's frozen set is exactly 0..sec)
#pragma unroll
                    for (int c = 0; c < 8; ++c)
                        if (c <= sec) {
#pragma unroll
                            for (int nb = 0; nb < 4; ++nb)
                                gll16(wrow + c * 2048 + nb * 512, &ring[ns][w][c][nb][0]);
                        }
                    gll4(b1 + ip * Hn + l,                   &sring[ns][w][0]);
                    gll4(W2 + ip * Hn + l,                   &sring[ns][w][64]);
                    gll4(nsT + (size_t)ip * B + rowbase + n, &sring[ns][w][128]);
                    gll4(b2 + ip,                            &sring[ns][w][192]);
                }
                __builtin_amdgcn_sched_barrier(0);   // glls may not sink below

                // ---- this step's scalars from slot sl (broadcast reads) ----
                floatx4 b1c[4], w2c[4];
#pragma unroll
                for (int nb = 0; nb < 4; ++nb) {
                    b1c[nb] = *(const floatx4*)&sring[sl][w][nb * 16 + q * 4];
                    w2c[nb] = *(const floatx4*)&sring[sl][w][64 + nb * 16 + q * 4];
                }
                const float nvc = sring[sl][w][128 + n];
                const float b2c = sring[sl][w][192];

                // ---- MFMAs from slot sl ----
                floatx4 aA[4], aB4[4];
#pragma unroll
                for (int nb = 0; nb < 4; ++nb) { aA[nb] = zf4; aB4[nb] = zf4; }

                if (ii != 0) {   // section's first step: z-chunk empty, chunk
                                 // sec not staged -> must skip (0*garbage=NaN)
                    short8 zi = __builtin_bit_cast(short8, ain);
#pragma unroll
                    for (int nb = 0; nb < 4; ++nb) {
                        short8 wfs = *(const short8*)&ring[sl][w][sec][nb][(size_t)l * 8];
                        aB4[nb] = __builtin_amdgcn_mfma_f32_16x16x32_bf16(wfs, zi, aB4[nb], 0, 0, 0);
                    }
                }
#pragma unroll
                for (int c = 0; c < 8; ++c)
                    if (c < sec) {
#pragma unroll
                        for (int nb = 0; nb < 4; ++nb) {
                            short8 wfc = *(const short8*)&ring[sl][w][c][nb][(size_t)l * 8];
                            aA[nb] = __builtin_amdgcn_mfma_f32_16x16x32_bf16(wfc, af[c], aA[nb], 0, 0, 0);
                        }
                    }

                // ---- epilogue: per-lane silu dot (16 hidden), 2-round shfl ----
                float ssum = 0.f;
#pragma unroll
                for (int nb = 0; nb < 4; ++nb) {
#pragma unroll
                    for (int r = 0; r < 4; ++r) {
                        float h = (aA[nb][r] + aB4[nb][r]) + b1c[nb][r];
                        ssum += __fdividef(h, 1.f + __expf(-h)) * w2c[nb][r];
                    }
                }
                ssum += __shfl_xor(ssum, 16);
                ssum += __shfl_xor(ssum, 32);
                const float z_ = ssum + b2c + nvc;

                // ---- in-register z insert (v4-validated; all static here) ----
                {
                    unsigned int zb = ((unsigned int)f2bf(z_)) << (16 * (e8 & 1));
                    const unsigned int msk = 0xFFFFu << (16 * (e8 & 1));
                    const int own = (q == ii8);          // q == ii>>3
                    const int wsel = (e8 >> 1) & 3;      // == (ii>>1)&3
#pragma unroll
                    for (int wd = 0; wd < 4; ++wd) {
                        unsigned int mg = (ain[wd] & ~msk) | zb;
                        ain[wd] = (own && (wsel == wd)) ? mg : ain[wd];
                    }
                }
                zz[e8] = z_;
            }
            // batched out flush: 8 steps = 32 B per row, lanes q==0
            if (q == 0) {
                float* op = out + (size_t)(rowbase + n) * Dn + sec * 32 + ii8 * 8;
                floatx4 o0 = {zz[0], zz[1], zz[2], zz[3]};
                floatx4 o1 = {zz[4], zz[5], zz[6], zz[7]};
                *(floatx4*)(op)     = o0;
                *(floatx4*)(op + 4) = o1;
            }
        }
    }
}

// ---------------------------------------------------------------------------
extern "C" void kernel_launch(void* const* d_in, const int* in_sizes, int n_in,
                              void* d_out, int out_size, void* d_ws, size_t ws_size,
                              hipStream_t stream) {
    const float* noise      = (const float*)d_in[0];
    const float* adj_logits = (const float*)d_in[1];
    const float* W1         = (const float*)d_in[2];
    const float* b1         = (const float*)d_in[3];
    const float* W2         = (const float*)d_in[4];
    const float* b2         = (const float*)d_in[5];
    const float* log_sigma  = (const float*)d_in[6];
    float* out = (float*)d_out;

    const int B = in_sizes[0] / Dn;                       // 8192
    // ws layout (16.78 MB total):
    //   [0, 8.39M)      : Wb   (bf16 fragment weights)
    //   [8.39M, 16.78M) : nsT  (fp32 transposed scaled noise);
    //                     sgm (256 KB) transiently occupies its start.
    unsigned short* Wb  = (unsigned short*)d_ws;
    float*          nsT = (float*)((char*)d_ws + (size_t)Dn * Dn * Hn * 2);
    float*          sgm = nsT;   // consumed by prep_wb before prep_nst overwrites

    prep_sgm<<<dim3(Dn), 256, 0, stream>>>(adj_logits, sgm);
    prep_wb<<<dim3(8, Dn), 256, 0, stream>>>(W1, sgm, Wb);
    prep_nst<<<dim3(B / 64, Dn / 64), 256, 0, stream>>>(noise, log_sigma, nsT, B);
    scm_main<<<dim3(B / 32), 128, 0, stream>>>(Wb, b1, W2, b2, nsT, out, B);
}

// Round 9
// 391.122 us; speedup vs baseline: 1.4295x; 1.4295x over previous
//
#include <hip/hip_runtime.h>
#include <math.h>

#define Dn 256
#define Hn 64

typedef __attribute__((ext_vector_type(8))) short short8;
typedef __attribute__((ext_vector_type(4))) float floatx4;
typedef __attribute__((ext_vector_type(4))) unsigned int uint4v;

static __device__ __forceinline__ unsigned short f2bf(float x) {
    unsigned int u = __float_as_uint(x);
    unsigned int r = (u + 0x7fffu + ((u >> 16) & 1u)) >> 16;   // RNE
    return (unsigned short)r;
}

// async global -> LDS, dest = wave-uniform base + lane*size; SOURCE is per-lane
static __device__ __forceinline__ void gll16(const unsigned short* g, unsigned short* l) {
    __builtin_amdgcn_global_load_lds(
        (const __attribute__((address_space(1))) unsigned int*)g,
        (__attribute__((address_space(3))) unsigned int*)l, 16, 0, 0);
}
static __device__ __forceinline__ void gll4(const float* g, float* l) {
    __builtin_amdgcn_global_load_lds(
        (const __attribute__((address_space(1))) unsigned int*)g,
        (__attribute__((address_space(3))) unsigned int*)l, 4, 0, 0);
}

// ---------------------------------------------------------------------------
// prep_sgm: sgm[i*Dn + j] = sigmoid(adj[j*Dn + i]) * (j != i)
// grid 256 (i), block 256 (j)
// ---------------------------------------------------------------------------
__global__ __launch_bounds__(256) void prep_sgm(const float* __restrict__ adj,
                                                float* __restrict__ sgm) {
    const int i = blockIdx.x, j = threadIdx.x;
    float m = 0.f;
    if (j != i) m = 1.f / (1.f + __expf(-adj[(size_t)j * Dn + i]));
    sgm[(size_t)i * Dn + j] = m;
}

// ---------------------------------------------------------------------------
// prep_wb: masked bf16 weights in MFMA fragment layout (validated R2/v2/v4).
// Fragment (i, c, nb, lane, e) <-> kk = nb*16 + (lane&15), j = c*32 + (lane>>4)*8 + e
// Wb offset (ushort): (((i*8 + c)*4 + nb)*64 + lane)*8 + e
// Used as the A-operand of mfma(W, Z): M-index = lane&15 = hidden.
// grid (8, 256) = (c, i), block 256
// ---------------------------------------------------------------------------
__global__ __launch_bounds__(256) void prep_wb(const float* __restrict__ W1,
                                               const float* __restrict__ sgm,
                                               unsigned short* __restrict__ Wb) {
    const int c = blockIdx.x, i = blockIdx.y;
    const int t = threadIdx.x;
    const int nb = t >> 6, l = t & 63;
    const int kk = nb * 16 + (l & 15);
    const int jb = c * 32 + ((l >> 4) & 3) * 8;
    const float* wp = W1 + ((size_t)i * Hn + kk) * Dn + jb;
    const float* sp = sgm + (size_t)i * Dn + jb;
    unsigned short v[8];
#pragma unroll
    for (int e = 0; e < 8; ++e) v[e] = f2bf(wp[e] * sp[e]);
    unsigned short* dst = Wb + ((((size_t)i * 8 + c) * 4 + nb) * 64 + l) * 8;
    *(short8*)dst = *(const short8*)v;
}

// ---------------------------------------------------------------------------
// prep_nst: nsT[d*B + b] = exp(log_sigma[d]) * noise[b*Dn + d]  (64x64 tiles)
// grid (B/64, Dn/64), block 256
// ---------------------------------------------------------------------------
__global__ __launch_bounds__(256) void prep_nst(const float* __restrict__ noise,
                                                const float* __restrict__ ls,
                                                float* __restrict__ nsT, int B) {
    __shared__ float tile[64][65];
    const int bi = blockIdx.x * 64, dj = blockIdx.y * 64;
    const int t = threadIdx.x, c = t & 63, rq = t >> 6;
#pragma unroll
    for (int it = 0; it < 16; ++it) {
        int b = bi + it * 4 + rq;
        tile[it * 4 + rq][c] = noise[(size_t)b * Dn + dj + c];
    }
    __syncthreads();
#pragma unroll
    for (int it = 0; it < 16; ++it) {
        int d = dj + it * 4 + rq;
        float sg = __expf(ls[d]);
        nsT[(size_t)d * B + bi + c] = tile[c][it * 4 + rq] * sg;
    }
}

// ---------------------------------------------------------------------------
// scm_main (v9): SHARED weight ring + GROUP-level pipelining.
//   Lesson from v8 (491us, pinned glls): per-step vmcnt(0) drain + per-wave
//   duplicated staging + 36 serialized ds_reads dominate — not load-issue
//   placement. v9 restructures:
//     - block = 128 = 2 waves; the waves SHARE one staged weight ring
//       (weights are wave-invariant) -> per-CU staging traffic halves.
//     - GROUP = 2 steps. One __syncthreads per group: drains glls issued a
//       full group earlier (landed -> cheap) and closes the WAR window on
//       the slot being overwritten. Then glls for group g+1 are issued;
//       they sit between the barrier and the body's first ds_read
//       (compiler cannot reorder LDS writes past LDS reads) -> trapped
//       early, a full group (~1000 cyc) in flight.
//     - body: 2 steps from slot cur. In-progress MFMA UNCONDITIONAL
//       (chunk sec is always staged; ain==0 at section start gives exact 0).
//     - z history per-wave in registers (v4-validated insert, runtime form).
//     - out-stores deferred one group so they never block a drain.
// grid: B/32, block 128. LDS 138 KB -> 1 block/CU.
// ---------------------------------------------------------------------------
__global__ __launch_bounds__(128, 1) void scm_main(const unsigned short* __restrict__ Wb,
                                                   const float* __restrict__ b1,
                                                   const float* __restrict__ W2,
                                                   const float* __restrict__ b2,
                                                   const float* __restrict__ nsT,
                                                   float* __restrict__ out, int B) {
    // [slot][rowInGroup][chunk][nb][lane*8]  (shared by both waves) = 128 KB
    __shared__ __align__(16) unsigned short ring[2][2][8][4][512];
    // [slot][rowInGroup][0..63 b1 | 64..127 W2 | 128..191 b2dup] = 6 KB
    __shared__ __align__(16) float srb[2][2][192];
    // [slot][wave][s*64 + lane] noise*sigma for THIS wave's rows = 4 KB
    __shared__ __align__(16) float srn[2][2][128];

    const int t = threadIdx.x;
    const int w = t >> 6, l = t & 63;
    const int n = l & 15, q = l >> 4;
    const int rowbase = blockIdx.x * 32 + w * 16;

    short8 af[8];                        // frozen z chunks (registers)
    uint4v ain = {0u, 0u, 0u, 0u};       // in-progress z chunk (registers)
    const floatx4 zf4 = {0.f, 0.f, 0.f, 0.f};
    float pz0 = 0.f, pz1 = 0.f;          // deferred out-store values

    // prologue: stage group 0 (rows 0,1; chunk 0 only) into slot 0.
    // wave w stages row w's weights + scalars; each wave stages its own nv.
    {
        const unsigned short* wrow = Wb + (size_t)w * 16384 + (size_t)l * 8;
#pragma unroll
        for (int nb = 0; nb < 4; ++nb) gll16(wrow + nb * 512, &ring[0][w][0][nb][0]);
        gll4(b1 + w * Hn + l, &srb[0][w][0]);
        gll4(W2 + w * Hn + l, &srb[0][w][64]);
        gll4(b2 + w,          &srb[0][w][128]);
        gll4(nsT + rowbase + (l & 15),             &srn[0][w][0]);
        gll4(nsT + (size_t)B + rowbase + (l & 15), &srn[0][w][64]);
    }

#pragma unroll
    for (int sec = 0; sec < 8; ++sec) {
#pragma unroll 1
        for (int gg = 0; gg < 16; ++gg) {
            const int i0 = sec * 32 + gg * 2;
            const int cur = gg & 1, ns = cur ^ 1;

            // one barrier per group: drains last group's glls (landed) and
            // closes the WAR window on slot ns.
            __syncthreads();

            // deferred out-store of previous group's z (never blocks a drain
            // that matters: a full group passes before the next barrier)
            if (q == 0 && i0 > 0) {
                float2 pv; pv.x = pz0; pv.y = pz1;
                *(float2*)(out + (size_t)(rowbase + n) * Dn + (i0 - 2)) = pv;
            }

            // ---- stage group g+1 (rows i0+2, i0+3) into slot ns ----
            if (i0 + 2 < 256) {
                const int rip  = i0 + 2 + w;        // wave w stages row +w
                const int secp = (i0 + 2) >> 5;     // next group's section
                const unsigned short* wrow = Wb + (size_t)rip * 16384 + (size_t)l * 8;
#pragma unroll
                for (int c = 0; c < 8; ++c)
                    if (c <= secp) {
#pragma unroll
                        for (int nb = 0; nb < 4; ++nb)
                            gll16(wrow + c * 2048 + nb * 512, &ring[ns][w][c][nb][0]);
                    }
                gll4(b1 + rip * Hn + l, &srb[ns][w][0]);
                gll4(W2 + rip * Hn + l, &srb[ns][w][64]);
                gll4(b2 + rip,          &srb[ns][w][128]);
                gll4(nsT + (size_t)(i0 + 2) * B + rowbase + (l & 15), &srn[ns][w][0]);
                gll4(nsT + (size_t)(i0 + 3) * B + rowbase + (l & 15), &srn[ns][w][64]);
            }
            __builtin_amdgcn_sched_barrier(0);

            // ---- group body: 2 steps from slot cur ----
            float zlocal[2];
#pragma unroll
            for (int s = 0; s < 2; ++s) {
                // scalars for step i0+s (row s of the group)
                floatx4 b1c[4], w2c[4];
#pragma unroll
                for (int nb = 0; nb < 4; ++nb) {
                    b1c[nb] = *(const floatx4*)&srb[cur][s][nb * 16 + q * 4];
                    w2c[nb] = *(const floatx4*)&srb[cur][s][64 + nb * 16 + q * 4];
                }
                const float b2c = srb[cur][s][128];
                const float nvc = srn[cur][w][s * 64 + n];

                floatx4 aA[4], aB4[4];
#pragma unroll
                for (int nb = 0; nb < 4; ++nb) { aA[nb] = zf4; aB4[nb] = zf4; }

                // in-progress chunk: UNCONDITIONAL (ain==0 at section start
                // contributes exact zero; chunk sec is always staged)
                {
                    short8 zi = __builtin_bit_cast(short8, ain);
#pragma unroll
                    for (int nb = 0; nb < 4; ++nb) {
                        short8 wfs = *(const short8*)&ring[cur][s][sec][nb][(size_t)l * 8];
                        aB4[nb] = __builtin_amdgcn_mfma_f32_16x16x32_bf16(wfs, zi, aB4[nb], 0, 0, 0);
                    }
                }
                // frozen chunks
#pragma unroll
                for (int c = 0; c < 8; ++c)
                    if (c < sec) {
#pragma unroll
                        for (int nb = 0; nb < 4; ++nb) {
                            short8 wfc = *(const short8*)&ring[cur][s][c][nb][(size_t)l * 8];
                            aA[nb] = __builtin_amdgcn_mfma_f32_16x16x32_bf16(wfc, af[c], aA[nb], 0, 0, 0);
                        }
                    }

                // epilogue: per-lane silu dot (16 hidden), 2-round shfl reduce
                float ssum = 0.f;
#pragma unroll
                for (int nb = 0; nb < 4; ++nb) {
#pragma unroll
                    for (int r = 0; r < 4; ++r) {
                        float h = (aA[nb][r] + aB4[nb][r]) + b1c[nb][r];
                        ssum += __fdividef(h, 1.f + __expf(-h)) * w2c[nb][r];
                    }
                }
                ssum += __shfl_xor(ssum, 16);
                ssum += __shfl_xor(ssum, 32);
                const float z_ = ssum + b2c + nvc;

                // in-register z insert (v4-validated runtime form):
                // ii = gg*2+s; sh = 16*s (static); wsel = gg&3; own = q==(gg>>2)
                {
                    unsigned int zb = ((unsigned int)f2bf(z_)) << (16 * s);
                    const unsigned int msk = 0xFFFFu << (16 * s);
                    const int own  = (q == (gg >> 2));
                    const int wsel = gg & 3;
#pragma unroll
                    for (int wd = 0; wd < 4; ++wd) {
                        unsigned int mg = (ain[wd] & ~msk) | zb;
                        ain[wd] = (own && (wsel == wd)) ? mg : ain[wd];
                    }
                }
                zlocal[s] = z_;
            }
            pz0 = zlocal[0]; pz1 = zlocal[1];
        }
        // section boundary: freeze the completed chunk
        if (sec < 7) {
            af[sec] = __builtin_bit_cast(short8, ain);
            ain = (uint4v){0u, 0u, 0u, 0u};
        }
    }

    // trailing store for the final group (i0 = 254)
    if (q == 0) {
        float2 pv; pv.x = pz0; pv.y = pz1;
        *(float2*)(out + (size_t)(rowbase + n) * Dn + 254) = pv;
    }
}

// ---------------------------------------------------------------------------
extern "C" void kernel_launch(void* const* d_in, const int* in_sizes, int n_in,
                              void* d_out, int out_size, void* d_ws, size_t ws_size,
                              hipStream_t stream) {
    const float* noise      = (const float*)d_in[0];
    const float* adj_logits = (const float*)d_in[1];
    const float* W1         = (const float*)d_in[2];
    const float* b1         = (const float*)d_in[3];
    const float* W2         = (const float*)d_in[4];
    const float* b2         = (const float*)d_in[5];
    const float* log_sigma  = (const float*)d_in[6];
    float* out = (float*)d_out;

    const int B = in_sizes[0] / Dn;                       // 8192
    // ws layout (16.78 MB total):
    //   [0, 8.39M)      : Wb   (bf16 fragment weights)
    //   [8.39M, 16.78M) : nsT  (fp32 transposed scaled noise);
    //                     sgm (256 KB) transiently occupies its start.
    unsigned short* Wb  = (unsigned short*)d_ws;
    float*          nsT = (float*)((char*)d_ws + (size_t)Dn * Dn * Hn * 2);
    float*          sgm = nsT;   // consumed by prep_wb before prep_nst overwrites

    prep_sgm<<<dim3(Dn), 256, 0, stream>>>(adj_logits, sgm);
    prep_wb<<<dim3(8, Dn), 256, 0, stream>>>(W1, sgm, Wb);
    prep_nst<<<dim3(B / 64, Dn / 64), 256, 0, stream>>>(noise, log_sigma, nsT, B);
    scm_main<<<dim3(B / 32), 128, 0, stream>>>(Wb, b1, W2, b2, nsT, out, B);
}